// Round 6
// baseline (69.451 us; speedup 1.0000x reference)
//
#include <hip/hip_runtime.h>
#include <hip/hip_bf16.h>

#define NB 8
#define NC 512
#define NT 1024
#define NHEADS 8
#define NCH 64
#define NGROUPS 32
#define NGC 16   // channels per group

typedef __attribute__((ext_vector_type(4))) unsigned short u16x4;
typedef __attribute__((ext_vector_type(8))) unsigned short u16x8;
typedef __attribute__((ext_vector_type(4))) float f32x4;
typedef __attribute__((ext_vector_type(8))) __bf16 bfv8;

// hardware f32->bf16 RNE (single v_cvt op)
static __device__ __forceinline__ unsigned short f2bf(float f) {
    __bf16 h = (__bf16)f;
    return __builtin_bit_cast(unsigned short, h);
}

static __device__ __forceinline__ f32x4 mfma_bf16(u16x8 a, u16x8 b, f32x4 c) {
    return __builtin_amdgcn_mfma_f32_16x16x32_bf16(
        __builtin_bit_cast(bfv8, a), __builtin_bit_cast(bfv8, b), c, 0, 0, 0);
}

// async global->LDS, 16B per lane; dest is wave-uniform base + lane*16
static __device__ __forceinline__ void gl_lds16(const unsigned short* g, unsigned short* l) {
    __builtin_amdgcn_global_load_lds(
        (const __attribute__((address_space(1))) unsigned int*)g,
        (__attribute__((address_space(3))) unsigned int*)l, 16, 0, 0);
}

// ---------------- K1: GroupNorm (blocks 0..255) + w1 cvt (blocks 256..447) ----------------
__global__ __launch_bounds__(512) void k_gn_w1(const float* __restrict__ x,
                                               const float* __restrict__ gw,
                                               const float* __restrict__ gb,
                                               const float* __restrict__ w1,
                                               unsigned short* __restrict__ xnT,
                                               unsigned short* __restrict__ w1b) {
    int tid = threadIdx.x;
    if (blockIdx.x >= 256) {   // w1 fp32 -> bf16
        int i = ((blockIdx.x - 256) * 512 + tid) * 8;
        f32x4 a = *(const f32x4*)(w1 + i);
        f32x4 b = *(const f32x4*)(w1 + i + 4);
        u16x8 o;
#pragma unroll
        for (int j = 0; j < 4; ++j) { o[j] = f2bf(a[j]); o[4 + j] = f2bf(b[j]); }
        *(u16x8*)(w1b + i) = o;
        return;
    }
    int b = blockIdx.x >> 5, g = blockIdx.x & 31;
    int half = tid >> 8, tl = tid & 255;
    int t4 = tl * 4;
    const float* xb = x + ((size_t)(b * NC + g * NGC + half * 8)) * NT;

    f32x4 vv[8];
    float s = 0.f, ss = 0.f;
#pragma unroll
    for (int cc = 0; cc < 8; ++cc) {
        f32x4 v = *(const f32x4*)(xb + cc * NT + t4);
        vv[cc] = v;
#pragma unroll
        for (int i = 0; i < 4; ++i) { s += v[i]; ss += v[i] * v[i]; }
    }
#pragma unroll
    for (int off = 1; off < 64; off <<= 1) { s += __shfl_xor(s, off); ss += __shfl_xor(ss, off); }
    __shared__ float rs_[8], rss[8];
    int w = tid >> 6;
    if ((tid & 63) == 0) { rs_[w] = s; rss[w] = ss; }
    __syncthreads();
    s = 0.f; ss = 0.f;
#pragma unroll
    for (int i = 0; i < 8; ++i) { s += rs_[i]; ss += rss[i]; }
    float mu  = s * (1.f / 16384.f);
    float var = ss * (1.f / 16384.f) - mu * mu;
    float rstd = rsqrtf(var + 1e-5f);

    float wgt[8], bia[8];
#pragma unroll
    for (int cc = 0; cc < 8; ++cc) {
        float ww = gw[g * NGC + half * 8 + cc] * rstd;
        wgt[cc] = ww;
        bia[cc] = gb[g * NGC + half * 8 + cc] - mu * ww;
    }
#pragma unroll
    for (int i = 0; i < 4; ++i) {
        unsigned short o[8];
#pragma unroll
        for (int cc = 0; cc < 8; ++cc) o[cc] = f2bf(vv[cc][i] * wgt[cc] + bia[cc]);
        unsigned short* dst = xnT + ((size_t)(b * NT + t4 + i)) * NC + g * NGC + half * 8;
        *(u16x8*)dst = *(u16x8*)o;
    }
}

// ---------------- K2: QKV GEMM ----------------
// 128x128 tile, BK=64 double-buffered, global_load_lds staging (swizzled).
// Epilogue writes q_t/k_t [b][h][t][c] (8B packed stores) and v natural [b][vc][t].
// q scale folds ch^-0.5 (0.125) AND log2(e) so attention uses raw v_exp (exp2).
__global__ __launch_bounds__(256) void k_qkv_gemm(const unsigned short* __restrict__ w1b,
                                                  const unsigned short* __restrict__ xnT,
                                                  const float* __restrict__ b1,
                                                  unsigned short* __restrict__ q_t,
                                                  unsigned short* __restrict__ k_t,
                                                  unsigned short* __restrict__ vbuf) {
    __shared__ unsigned short As[2 * 128 * 64];   // 32KB
    __shared__ unsigned short Bs[2 * 128 * 64];   // 32KB
    int bid = blockIdx.x;
    int lbid = (bid & 7) * 96 + (bid >> 3);   // XCD x owns batch x (768 = 8*96, bijective)
    int bb = lbid / 96;
    int rr_ = lbid % 96;
    int tm = rr_ >> 3, tn = rr_ & 7;
    int tid = threadIdx.x;
    int l = tid & 63, w = tid >> 6;
    int wm = w >> 1, wn = w & 1;
    int ll = l & 15, lg = l >> 4;
    int rl = l >> 3, sl = l & 7;
    int ssl = sl ^ rl;

    const unsigned short* Ag = w1b + (size_t)(tm * 128) * NC;
    const unsigned short* Bg = xnT + (size_t)(bb * NT + tn * 128) * NC;

    auto STAGE = [&](int k0, int buf) {
        unsigned short* dA = As + buf * 8192 + w * 32 * 64;
        unsigned short* dB = Bs + buf * 8192 + w * 32 * 64;
#pragma unroll
        for (int i = 0; i < 4; ++i) {
            int row = w * 32 + i * 8 + rl;    // row&7 == rl
            gl_lds16(Ag + (size_t)row * NC + k0 + ssl * 8, dA + i * 512);
            gl_lds16(Bg + (size_t)row * NC + k0 + ssl * 8, dB + i * 512);
        }
    };

    f32x4 acc[4][4] = {};
    STAGE(0, 0);
    __syncthreads();
    int cur = 0;
    for (int ks = 0; ks < 8; ++ks) {
        if (ks < 7) STAGE((ks + 1) * 64, cur ^ 1);
        const char* Ac = (const char*)(As + cur * 8192);
        const char* Bc = (const char*)(Bs + cur * 8192);
#pragma unroll
        for (int kk = 0; kk < 2; ++kk) {
            u16x8 af[4], bf[4];
#pragma unroll
            for (int m = 0; m < 4; ++m) {
                int row = wm * 64 + m * 16 + ll;
                af[m] = *(const u16x8*)(Ac + row * 128 + ((kk * 64 + lg * 16) ^ ((row & 7) << 4)));
            }
#pragma unroll
            for (int n = 0; n < 4; ++n) {
                int row = wn * 64 + n * 16 + ll;
                bf[n] = *(const u16x8*)(Bc + row * 128 + ((kk * 64 + lg * 16) ^ ((row & 7) << 4)));
            }
#pragma unroll
            for (int m = 0; m < 4; ++m)
#pragma unroll
                for (int n = 0; n < 4; ++n)
                    acc[m][n] = mfma_bf16(af[m], bf[n], acc[m][n]);
        }
        __syncthreads();
        cur ^= 1;
    }

    if (tm < 8) {   // q or k: write [b][h][t][c]
        int qk = tm >> 2;
        int h = (tm & 3) * 2 + wm;
        float sc = qk ? 1.f : 0.125f * 1.44269504088896f;  // q: ch^-0.5 * log2(e)
        int obase = tm * 128 + wm * 64;
        unsigned short* dst = (qk ? k_t : q_t) + ((size_t)(bb * 8 + h)) * NT * NCH;
#pragma unroll
        for (int m = 0; m < 4; ++m) {
#pragma unroll
            for (int n = 0; n < 4; ++n) {
                int t = tn * 128 + wn * 64 + n * 16 + ll;
                u16x4 pk;
#pragma unroll
                for (int r = 0; r < 4; ++r)
                    pk[r] = f2bf((acc[m][n][r] + b1[obase + m * 16 + lg * 4 + r]) * sc);
                *(u16x4*)(dst + (size_t)t * NCH + m * 16 + lg * 4) = pk;
            }
        }
    } else {        // v: natural [b][vc][t]
        int vcb = (tm - 8) * 128 + wm * 64;
#pragma unroll
        for (int m = 0; m < 4; ++m)
#pragma unroll
            for (int r = 0; r < 4; ++r) {
                int vc = vcb + m * 16 + lg * 4 + r;
                float bias = b1[1024 + vc];
#pragma unroll
                for (int n = 0; n < 4; ++n) {
                    int t = tn * 128 + wn * 64 + n * 16 + ll;
                    vbuf[(size_t)(bb * NC + vc) * NT + t] = f2bf(acc[m][n][r] + bias);
                }
            }
    }
}

// ---------------- K3: attention v4 (R3 structure + R5 VALU fixes) ----------------
// block = (b, h, 128-query tile); 4 waves x 32 q-rows (256 thr) -> per-block LDS
// read traffic = 4 x tile (half of 8-wave). K/V 64-key tiles double-buffered via
// global_load_lds (source-swizzled). No max subtraction (S~N(0,1)); softmax =
// exp2(S')/rowsum with log2e folded into q upstream.
#define SW1B(r) (((r) & 7) << 4)                          // K/V/O row swizzle (128B rows)
#define SW2B(t) ((((t) & 7) << 4) ^ (((t) & 8) << 2))     // P row swizzle
__global__ __launch_bounds__(256) void k_attn(const unsigned short* __restrict__ q_t,
                                              const unsigned short* __restrict__ k_t,
                                              const unsigned short* __restrict__ vbuf,
                                              const float* __restrict__ x,
                                              float* __restrict__ out) {
    __shared__ unsigned char smem[49152];
    unsigned short* sK = (unsigned short*)smem;            // [2][64][64] bf16, 16KB
    unsigned short* sV = (unsigned short*)(smem + 16384);  // [2][64][64] bf16, 16KB
    unsigned short* sP = (unsigned short*)(smem + 32768);  // [4][32][64] bf16, 16KB

    int lbid = ((blockIdx.x & 7) << 6) | (blockIdx.x >> 3);  // XCD x hosts batch x
    int b  = lbid >> 6;
    int h  = (lbid >> 3) & 7;
    int qt = lbid & 7;
    int t0 = qt * 128;

    int tid = threadIdx.x;
    int l = tid & 63, w = tid >> 6;
    int ll = l & 15, lg = l >> 4;
    int rl = l >> 3, sl = l & 7;
    int ssl = sl ^ rl;

    const unsigned short* Qg = q_t + ((size_t)((b * 8 + h) * NT + t0 + w * 32)) * NCH;
    const unsigned short* Kg = k_t + ((size_t)(b * 8 + h)) * NT * NCH;
    const unsigned short* Vg = vbuf + ((size_t)(b * NC + h * NCH)) * NT;

    u16x8 aq[2][2];
#pragma unroll
    for (int m = 0; m < 2; ++m)
#pragma unroll
        for (int kk = 0; kk < 2; ++kk)
            aq[m][kk] = *(const u16x8*)(Qg + (m * 16 + ll) * NCH + kk * 32 + lg * 8);

    f32x4 acc_o[2][4] = {};
    float rs[2][4] = {};

    auto STAGE = [&](int s0, int buf) {
        unsigned short* dK = sK + buf * 4096 + w * 1024;
        unsigned short* dV = sV + buf * 4096 + w * 1024;
#pragma unroll
        for (int i = 0; i < 2; ++i) {
            int row = w * 16 + i * 8 + rl;    // row&7 == rl
            gl_lds16(Kg + (size_t)(s0 + row) * NCH + ssl * 8, dK + i * 512);
            gl_lds16(Vg + (size_t)row * NT + s0 + ssl * 8, dV + i * 512);
        }
    };

    STAGE(0, 0);
    __syncthreads();

    char* sPw = (char*)(sP + w * 2048);   // per-wave [32][64] bf16 (4KB)
    int cur = 0;
    for (int tile = 0; tile < 16; ++tile) {
        if (tile < 15) STAGE((tile + 1) * 64, cur ^ 1);
        const char* Kc = (const char*)(sK + cur * 4096);
        const char* Vc = (const char*)(sV + cur * 4096);

        // S = Q K^T  (D[t 32][s 64] per wave)
        f32x4 sc_[2][4];
#pragma unroll
        for (int j = 0; j < 4; ++j) {
            int row = j * 16 + ll;
            int sw = SW1B(row);
            u16x8 b0 = *(const u16x8*)(Kc + row * 128 + ((lg * 16) ^ sw));
            u16x8 b1v = *(const u16x8*)(Kc + row * 128 + ((64 + lg * 16) ^ sw));
            f32x4 z = {0.f, 0.f, 0.f, 0.f};
            sc_[0][j] = mfma_bf16(aq[0][1], b1v, mfma_bf16(aq[0][0], b0, z));
            sc_[1][j] = mfma_bf16(aq[1][1], b1v, mfma_bf16(aq[1][0], b0, z));
        }

        // P = exp2(S) -> per-wave LDS (swizzled); accumulate row sums
#pragma unroll
        for (int m = 0; m < 2; ++m)
#pragma unroll
            for (int j = 0; j < 4; ++j)
#pragma unroll
                for (int r = 0; r < 4; ++r) {
                    float p = __builtin_amdgcn_exp2f(sc_[m][j][r]);
                    rs[m][r] += p;
                    int t = m * 16 + lg * 4 + r;
                    *(unsigned short*)(sPw + t * 128 + (((j * 16 + ll) * 2) ^ SW2B(t))) = f2bf(p);
                }

        // O += P V^T  (D[t 32][c 64])
        u16x8 ap[2][2];
#pragma unroll
        for (int m = 0; m < 2; ++m) {
            int t = m * 16 + ll;
            int sw = SW2B(t);
#pragma unroll
            for (int kk = 0; kk < 2; ++kk)
                ap[m][kk] = *(const u16x8*)(sPw + t * 128 + ((kk * 64 + lg * 16) ^ sw));
        }
#pragma unroll
        for (int n = 0; n < 4; ++n) {
            int row = n * 16 + ll;
            int sw = SW1B(row);
#pragma unroll
            for (int kk = 0; kk < 2; ++kk) {
                u16x8 bv = *(const u16x8*)(Vc + row * 128 + ((kk * 64 + lg * 16) ^ sw));
                acc_o[0][n] = mfma_bf16(ap[0][kk], bv, acc_o[0][n]);
                acc_o[1][n] = mfma_bf16(ap[1][kk], bv, acc_o[1][n]);
            }
        }
        __syncthreads();   // drains staging vmcnt + guards buffer swap
        cur ^= 1;
    }

    // row-sum reduce within 16-lane groups
    float rinv[2][4];
#pragma unroll
    for (int m = 0; m < 2; ++m)
#pragma unroll
        for (int r = 0; r < 4; ++r) {
            float s = rs[m][r];
            s += __shfl_xor(s, 1); s += __shfl_xor(s, 2);
            s += __shfl_xor(s, 4); s += __shfl_xor(s, 8);
            rinv[m][r] = 1.f / s;
        }

    // epilogue: O -> per-wave LDS [c 64][t 32] f32 (swizzled), then coalesced out+residual
    char* sO = (char*)(smem + w * 8192);   // reuses sK/sV (all waves past last read)
#pragma unroll
    for (int m = 0; m < 2; ++m)
#pragma unroll
        for (int n = 0; n < 4; ++n) {
            int c = n * 16 + ll;
            f32x4 o4;
#pragma unroll
            for (int r = 0; r < 4; ++r) o4[r] = acc_o[m][n][r] * rinv[m][r];
            *(f32x4*)(sO + c * 128 + ((m * 64 + lg * 16) ^ SW1B(c))) = o4;
        }
#pragma unroll
    for (int i2 = 0; i2 < 8; ++i2) {
        int c = i2 * 8 + rl;
        f32x4 o4 = *(const f32x4*)(sO + c * 128 + ((sl * 16) ^ SW1B(c)));
        size_t gidx = ((size_t)(b * NC + h * NCH + c)) * NT + t0 + w * 32 + sl * 4;
        f32x4 xv = *(const f32x4*)(x + gidx);
#pragma unroll
        for (int q = 0; q < 4; ++q) o4[q] += xv[q];
        *(f32x4*)(out + gidx) = o4;
    }
}

extern "C" void kernel_launch(void* const* d_in, const int* in_sizes, int n_in,
                              void* d_out, int out_size, void* d_ws, size_t ws_size,
                              hipStream_t stream) {
    (void)in_sizes; (void)n_in; (void)out_size; (void)ws_size;
    const float* x  = (const float*)d_in[0];
    const float* gw = (const float*)d_in[1];
    const float* gb = (const float*)d_in[2];
    const float* w1 = (const float*)d_in[3];
    const float* b1 = (const float*)d_in[4];
    float* out = (float*)d_out;

    char* ws = (char*)d_ws;
    unsigned short* w1b  = (unsigned short*)(ws);                        // 1.5 MB
    unsigned short* xnT  = (unsigned short*)(ws + (size_t)(2u << 20));   // 8.39 MB
    unsigned short* q_t  = (unsigned short*)(ws + (size_t)(11u << 20));  // 8.39 MB
    unsigned short* k_t  = (unsigned short*)(ws + (size_t)(20u << 20));  // 8.39 MB
    unsigned short* vbuf = (unsigned short*)(ws + (size_t)(29u << 20));  // 8.39 MB

    k_gn_w1<<<dim3(448), dim3(512), 0, stream>>>(x, gw, gb, w1, xnT, w1b);
    k_qkv_gemm<<<dim3(768), dim3(256), 0, stream>>>(w1b, xnT, b1, q_t, k_t, vbuf);
    k_attn<<<dim3(512), dim3(256), 0, stream>>>(q_t, k_t, vbuf, x, out);
}

// Round 7
// 67.820 us; speedup vs baseline: 1.0240x; 1.0240x over previous
//
#include <hip/hip_runtime.h>
#include <hip/hip_bf16.h>

#define NB 8
#define NC 512
#define NT 1024
#define NHEADS 8
#define NCH 64
#define NGROUPS 32
#define NGC 16   // channels per group

typedef __attribute__((ext_vector_type(4))) unsigned short u16x4;
typedef __attribute__((ext_vector_type(8))) unsigned short u16x8;
typedef __attribute__((ext_vector_type(4))) float f32x4;
typedef __attribute__((ext_vector_type(8))) __bf16 bfv8;

// hardware f32->bf16 RNE (single v_cvt op; compiler packs pairs to v_cvt_pk_bf16_f32)
static __device__ __forceinline__ unsigned short f2bf(float f) {
    __bf16 h = (__bf16)f;
    return __builtin_bit_cast(unsigned short, h);
}

static __device__ __forceinline__ f32x4 mfma_bf16(u16x8 a, u16x8 b, f32x4 c) {
    return __builtin_amdgcn_mfma_f32_16x16x32_bf16(
        __builtin_bit_cast(bfv8, a), __builtin_bit_cast(bfv8, b), c, 0, 0, 0);
}

// async global->LDS, 16B per lane; dest is wave-uniform base + lane*16
static __device__ __forceinline__ void gl_lds16(const unsigned short* g, unsigned short* l) {
    __builtin_amdgcn_global_load_lds(
        (const __attribute__((address_space(1))) unsigned int*)g,
        (__attribute__((address_space(3))) unsigned int*)l, 16, 0, 0);
}

// ---------------- K1: GroupNorm (blocks 0..255) + w1 cvt (blocks 256..447) ----------------
__global__ __launch_bounds__(512) void k_gn_w1(const float* __restrict__ x,
                                               const float* __restrict__ gw,
                                               const float* __restrict__ gb,
                                               const float* __restrict__ w1,
                                               unsigned short* __restrict__ xnT,
                                               unsigned short* __restrict__ w1b) {
    int tid = threadIdx.x;
    if (blockIdx.x >= 256) {   // w1 fp32 -> bf16
        int i = ((blockIdx.x - 256) * 512 + tid) * 8;
        f32x4 a = *(const f32x4*)(w1 + i);
        f32x4 b = *(const f32x4*)(w1 + i + 4);
        u16x8 o;
#pragma unroll
        for (int j = 0; j < 4; ++j) { o[j] = f2bf(a[j]); o[4 + j] = f2bf(b[j]); }
        *(u16x8*)(w1b + i) = o;
        return;
    }
    int b = blockIdx.x >> 5, g = blockIdx.x & 31;
    int half = tid >> 8, tl = tid & 255;
    int t4 = tl * 4;
    const float* xb = x + ((size_t)(b * NC + g * NGC + half * 8)) * NT;

    f32x4 vv[8];
    float s = 0.f, ss = 0.f;
#pragma unroll
    for (int cc = 0; cc < 8; ++cc) {
        f32x4 v = *(const f32x4*)(xb + cc * NT + t4);
        vv[cc] = v;
#pragma unroll
        for (int i = 0; i < 4; ++i) { s += v[i]; ss += v[i] * v[i]; }
    }
#pragma unroll
    for (int off = 1; off < 64; off <<= 1) { s += __shfl_xor(s, off); ss += __shfl_xor(ss, off); }
    __shared__ float rs_[8], rss[8];
    int w = tid >> 6;
    if ((tid & 63) == 0) { rs_[w] = s; rss[w] = ss; }
    __syncthreads();
    s = 0.f; ss = 0.f;
#pragma unroll
    for (int i = 0; i < 8; ++i) { s += rs_[i]; ss += rss[i]; }
    float mu  = s * (1.f / 16384.f);
    float var = ss * (1.f / 16384.f) - mu * mu;
    float rstd = rsqrtf(var + 1e-5f);

    float wgt[8], bia[8];
#pragma unroll
    for (int cc = 0; cc < 8; ++cc) {
        float ww = gw[g * NGC + half * 8 + cc] * rstd;
        wgt[cc] = ww;
        bia[cc] = gb[g * NGC + half * 8 + cc] - mu * ww;
    }
#pragma unroll
    for (int i = 0; i < 4; ++i) {
        unsigned short o[8];
#pragma unroll
        for (int cc = 0; cc < 8; ++cc) o[cc] = f2bf(vv[cc][i] * wgt[cc] + bia[cc]);
        unsigned short* dst = xnT + ((size_t)(b * NT + t4 + i)) * NC + g * NGC + half * 8;
        *(u16x8*)dst = *(u16x8*)o;
    }
}

// ---------------- K2: QKV GEMM ----------------
// 128x128 tile, BK=64 double-buffered, global_load_lds staging (swizzled).
// Epilogue writes q_t/k_t [b][h][t][c] (8B packed stores) and v natural [b][vc][t].
// q scale folds ch^-0.5 (0.125) AND log2(e) so attention uses raw v_exp (exp2).
__global__ __launch_bounds__(256) void k_qkv_gemm(const unsigned short* __restrict__ w1b,
                                                  const unsigned short* __restrict__ xnT,
                                                  const float* __restrict__ b1,
                                                  unsigned short* __restrict__ q_t,
                                                  unsigned short* __restrict__ k_t,
                                                  unsigned short* __restrict__ vbuf) {
    __shared__ unsigned short As[2 * 128 * 64];   // 32KB
    __shared__ unsigned short Bs[2 * 128 * 64];   // 32KB
    int bid = blockIdx.x;
    int lbid = (bid & 7) * 96 + (bid >> 3);   // XCD x owns batch x (768 = 8*96, bijective)
    int bb = lbid / 96;
    int rr_ = lbid % 96;
    int tm = rr_ >> 3, tn = rr_ & 7;
    int tid = threadIdx.x;
    int l = tid & 63, w = tid >> 6;
    int wm = w >> 1, wn = w & 1;
    int ll = l & 15, lg = l >> 4;
    int rl = l >> 3, sl = l & 7;
    int ssl = sl ^ rl;

    const unsigned short* Ag = w1b + (size_t)(tm * 128) * NC;
    const unsigned short* Bg = xnT + (size_t)(bb * NT + tn * 128) * NC;

    auto STAGE = [&](int k0, int buf) {
        unsigned short* dA = As + buf * 8192 + w * 32 * 64;
        unsigned short* dB = Bs + buf * 8192 + w * 32 * 64;
#pragma unroll
        for (int i = 0; i < 4; ++i) {
            int row = w * 32 + i * 8 + rl;    // row&7 == rl
            gl_lds16(Ag + (size_t)row * NC + k0 + ssl * 8, dA + i * 512);
            gl_lds16(Bg + (size_t)row * NC + k0 + ssl * 8, dB + i * 512);
        }
    };

    f32x4 acc[4][4] = {};
    STAGE(0, 0);
    __syncthreads();
    int cur = 0;
    for (int ks = 0; ks < 8; ++ks) {
        if (ks < 7) STAGE((ks + 1) * 64, cur ^ 1);
        const char* Ac = (const char*)(As + cur * 8192);
        const char* Bc = (const char*)(Bs + cur * 8192);
#pragma unroll
        for (int kk = 0; kk < 2; ++kk) {
            u16x8 af[4], bf[4];
#pragma unroll
            for (int m = 0; m < 4; ++m) {
                int row = wm * 64 + m * 16 + ll;
                af[m] = *(const u16x8*)(Ac + row * 128 + ((kk * 64 + lg * 16) ^ ((row & 7) << 4)));
            }
#pragma unroll
            for (int n = 0; n < 4; ++n) {
                int row = wn * 64 + n * 16 + ll;
                bf[n] = *(const u16x8*)(Bc + row * 128 + ((kk * 64 + lg * 16) ^ ((row & 7) << 4)));
            }
#pragma unroll
            for (int m = 0; m < 4; ++m)
#pragma unroll
                for (int n = 0; n < 4; ++n)
                    acc[m][n] = mfma_bf16(af[m], bf[n], acc[m][n]);
        }
        __syncthreads();
        cur ^= 1;
    }

    if (tm < 8) {   // q or k: write [b][h][t][c]
        int qk = tm >> 2;
        int h = (tm & 3) * 2 + wm;
        float sc = qk ? 1.f : 0.125f * 1.44269504088896f;  // q: ch^-0.5 * log2(e)
        int obase = tm * 128 + wm * 64;
        unsigned short* dst = (qk ? k_t : q_t) + ((size_t)(bb * 8 + h)) * NT * NCH;
#pragma unroll
        for (int m = 0; m < 4; ++m) {
#pragma unroll
            for (int n = 0; n < 4; ++n) {
                int t = tn * 128 + wn * 64 + n * 16 + ll;
                u16x4 pk;
#pragma unroll
                for (int r = 0; r < 4; ++r)
                    pk[r] = f2bf((acc[m][n][r] + b1[obase + m * 16 + lg * 4 + r]) * sc);
                *(u16x4*)(dst + (size_t)t * NCH + m * 16 + lg * 4) = pk;
            }
        }
    } else {        // v: natural [b][vc][t]
        int vcb = (tm - 8) * 128 + wm * 64;
#pragma unroll
        for (int m = 0; m < 4; ++m)
#pragma unroll
            for (int r = 0; r < 4; ++r) {
                int vc = vcb + m * 16 + lg * 4 + r;
                float bias = b1[1024 + vc];
#pragma unroll
                for (int n = 0; n < 4; ++n) {
                    int t = tn * 128 + wn * 64 + n * 16 + ll;
                    vbuf[(size_t)(bb * NC + vc) * NT + t] = f2bf(acc[m][n][r] + bias);
                }
            }
    }
}

// ---------------- K3: attention v5 (swapped-QK -> packed b64 P writes) ----------------
// block = (b, h, 128-query tile); 4 waves x 32 q-rows. K/V 64-key tiles
// double-buffered via global_load_lds (source-swizzled).
// QK computed as S^T = mfma(K,Q): lane holds col t=ll, rows s=lg*4+r
//  -> 4 consecutive s per acc reg -> one 8B packed P write (vs 4 scalar).
// P LDS layout [t 32][s 64] == PV A-frag layout; XOR (t&7)<<4 swizzle both sides.
// No max subtraction (S~N(0,1)); softmax = exp2(S')/rowsum, log2e folded into q.
#define SW1B(r) (((r) & 7) << 4)                          // K/V/O row swizzle (128B rows)
__global__ __launch_bounds__(256) void k_attn(const unsigned short* __restrict__ q_t,
                                              const unsigned short* __restrict__ k_t,
                                              const unsigned short* __restrict__ vbuf,
                                              const float* __restrict__ x,
                                              float* __restrict__ out) {
    __shared__ unsigned char smem[49152];
    unsigned short* sK = (unsigned short*)smem;            // [2][64][64] bf16, 16KB
    unsigned short* sV = (unsigned short*)(smem + 16384);  // [2][64][64] bf16, 16KB
    unsigned short* sP = (unsigned short*)(smem + 32768);  // [4][32][64] bf16, 16KB

    int lbid = ((blockIdx.x & 7) << 6) | (blockIdx.x >> 3);  // XCD x hosts batch x
    int b  = lbid >> 6;
    int h  = (lbid >> 3) & 7;
    int qt = lbid & 7;
    int t0 = qt * 128;

    int tid = threadIdx.x;
    int l = tid & 63, w = tid >> 6;
    int ll = l & 15, lg = l >> 4;
    int rl = l >> 3, sl = l & 7;
    int ssl = sl ^ rl;

    const unsigned short* Qg = q_t + ((size_t)((b * 8 + h) * NT + t0 + w * 32)) * NCH;
    const unsigned short* Kg = k_t + ((size_t)(b * 8 + h)) * NT * NCH;
    const unsigned short* Vg = vbuf + ((size_t)(b * NC + h * NCH)) * NT;

    u16x8 aq[2][2];
#pragma unroll
    for (int m = 0; m < 2; ++m)
#pragma unroll
        for (int kk = 0; kk < 2; ++kk)
            aq[m][kk] = *(const u16x8*)(Qg + (m * 16 + ll) * NCH + kk * 32 + lg * 8);

    f32x4 acc_o[2][4] = {};
    float rs[2] = {};

    auto STAGE = [&](int s0, int buf) {
        unsigned short* dK = sK + buf * 4096 + w * 1024;
        unsigned short* dV = sV + buf * 4096 + w * 1024;
#pragma unroll
        for (int i = 0; i < 2; ++i) {
            int row = w * 16 + i * 8 + rl;    // row&7 == rl
            gl_lds16(Kg + (size_t)(s0 + row) * NCH + ssl * 8, dK + i * 512);
            gl_lds16(Vg + (size_t)row * NT + s0 + ssl * 8, dV + i * 512);
        }
    };

    STAGE(0, 0);
    __syncthreads();

    char* sPw = (char*)(sP + w * 2048);   // per-wave [32 t][64 s] bf16 (4KB)
    int cur = 0;
    for (int tile = 0; tile < 16; ++tile) {
        if (tile < 15) STAGE((tile + 1) * 64, cur ^ 1);
        const char* Kc = (const char*)(sK + cur * 4096);
        const char* Vc = (const char*)(sV + cur * 4096);

        // S^T = K Q^T  (swapped operands): D[s 16][t 16] per (m,j);
        // lane: col t = m*16+ll, rows s = j*16 + lg*4 + r
        f32x4 sc_[2][4];
#pragma unroll
        for (int j = 0; j < 4; ++j) {
            int row = j * 16 + ll;
            int sw = SW1B(row);
            u16x8 b0 = *(const u16x8*)(Kc + row * 128 + ((lg * 16) ^ sw));
            u16x8 b1v = *(const u16x8*)(Kc + row * 128 + ((64 + lg * 16) ^ sw));
            f32x4 z = {0.f, 0.f, 0.f, 0.f};
            sc_[0][j] = mfma_bf16(b1v, aq[0][1], mfma_bf16(b0, aq[0][0], z));
            sc_[1][j] = mfma_bf16(b1v, aq[1][1], mfma_bf16(b0, aq[1][0], z));
        }

        // P = exp2(S); 4 consecutive s per reg -> packed 8B write; scalar rowsum
#pragma unroll
        for (int m = 0; m < 2; ++m) {
            int t = m * 16 + ll;
            int sw = (t & 7) << 4;
#pragma unroll
            for (int j = 0; j < 4; ++j) {
                float p0 = __builtin_amdgcn_exp2f(sc_[m][j][0]);
                float p1 = __builtin_amdgcn_exp2f(sc_[m][j][1]);
                float p2 = __builtin_amdgcn_exp2f(sc_[m][j][2]);
                float p3 = __builtin_amdgcn_exp2f(sc_[m][j][3]);
                rs[m] += (p0 + p1) + (p2 + p3);
                u16x4 pk = {f2bf(p0), f2bf(p1), f2bf(p2), f2bf(p3)};
                *(u16x4*)(sPw + t * 128 + ((j * 32 + lg * 8) ^ sw)) = pk;
            }
        }

        // O += P V^T  (D[t 32][c 64]); P reads == A-frag layout directly
        u16x8 ap[2][2];
#pragma unroll
        for (int m = 0; m < 2; ++m) {
            int t = m * 16 + ll;
            int sw = (t & 7) << 4;
#pragma unroll
            for (int kk = 0; kk < 2; ++kk)
                ap[m][kk] = *(const u16x8*)(sPw + t * 128 + ((kk * 64 + lg * 16) ^ sw));
        }
#pragma unroll
        for (int n = 0; n < 4; ++n) {
            int row = n * 16 + ll;
            int sw = SW1B(row);
#pragma unroll
            for (int kk = 0; kk < 2; ++kk) {
                u16x8 bv = *(const u16x8*)(Vc + row * 128 + ((kk * 64 + lg * 16) ^ sw));
                acc_o[0][n] = mfma_bf16(ap[0][kk], bv, acc_o[0][n]);
                acc_o[1][n] = mfma_bf16(ap[1][kk], bv, acc_o[1][n]);
            }
        }
        __syncthreads();   // drains staging vmcnt + guards buffer swap
        cur ^= 1;
    }

    // rowsum: lane holds rs for t = m*16+ll; reduce across the 4 lg replicas
    float rinv[2][4];
#pragma unroll
    for (int m = 0; m < 2; ++m) {
        float s = rs[m];
        s += __shfl_xor(s, 16);
        s += __shfl_xor(s, 32);
        // redistribute to PV-accumulator lanes: t = m*16 + lg*4 + r lives at ll = lg*4+r
#pragma unroll
        for (int r = 0; r < 4; ++r)
            rinv[m][r] = 1.f / __shfl(s, (l & 48) + lg * 4 + r);
    }

    // epilogue: O -> per-wave LDS [c 64][t 32] f32 (swizzled), then coalesced out+residual
    char* sO = (char*)(smem + w * 8192);   // reuses sK/sV (all waves past last read)
#pragma unroll
    for (int m = 0; m < 2; ++m)
#pragma unroll
        for (int n = 0; n < 4; ++n) {
            int c = n * 16 + ll;
            f32x4 o4;
#pragma unroll
            for (int r = 0; r < 4; ++r) o4[r] = acc_o[m][n][r] * rinv[m][r];
            *(f32x4*)(sO + c * 128 + ((m * 64 + lg * 16) ^ SW1B(c))) = o4;
        }
#pragma unroll
    for (int i2 = 0; i2 < 8; ++i2) {
        int c = i2 * 8 + rl;
        f32x4 o4 = *(const f32x4*)(sO + c * 128 + ((sl * 16) ^ SW1B(c)));
        size_t gidx = ((size_t)(b * NC + h * NCH + c)) * NT + t0 + w * 32 + sl * 4;
        f32x4 xv = *(const f32x4*)(x + gidx);
#pragma unroll
        for (int q = 0; q < 4; ++q) o4[q] += xv[q];
        *(f32x4*)(out + gidx) = o4;
    }
}

extern "C" void kernel_launch(void* const* d_in, const int* in_sizes, int n_in,
                              void* d_out, int out_size, void* d_ws, size_t ws_size,
                              hipStream_t stream) {
    (void)in_sizes; (void)n_in; (void)out_size; (void)ws_size;
    const float* x  = (const float*)d_in[0];
    const float* gw = (const float*)d_in[1];
    const float* gb = (const float*)d_in[2];
    const float* w1 = (const float*)d_in[3];
    const float* b1 = (const float*)d_in[4];
    float* out = (float*)d_out;

    char* ws = (char*)d_ws;
    unsigned short* w1b  = (unsigned short*)(ws);                        // 1.5 MB
    unsigned short* xnT  = (unsigned short*)(ws + (size_t)(2u << 20));   // 8.39 MB
    unsigned short* q_t  = (unsigned short*)(ws + (size_t)(11u << 20));  // 8.39 MB
    unsigned short* k_t  = (unsigned short*)(ws + (size_t)(20u << 20));  // 8.39 MB
    unsigned short* vbuf = (unsigned short*)(ws + (size_t)(29u << 20));  // 8.39 MB

    k_gn_w1<<<dim3(448), dim3(512), 0, stream>>>(x, gw, gb, w1, xnT, w1b);
    k_qkv_gemm<<<dim3(768), dim3(256), 0, stream>>>(w1b, xnT, b1, q_t, k_t, vbuf);
    k_attn<<<dim3(512), dim3(256), 0, stream>>>(q_t, k_t, vbuf, x, out);
}